// Round 2
// baseline (3080.767 us; speedup 1.0000x reference)
//
#include <hip/hip_runtime.h>
#include <math.h>

// Problem constants
#define BB 8
#define CC 3
#define DD 24
#define HH 128
#define WW 128
#define HW (HH * WW)
#define OCC 16
#define DOUT 22   // 24 - 2
#define HOUT 126
#define WOUT 126
#define DZH 11    // dz per group (2 groups per block)

// Per-tap 16-wide FMA into 16 named accumulators; weights broadcast from LDS
// as 4x float4 (wave-uniform address -> conflict-free broadcast ds_read_b128).
#define TAP(S, T, XV)                                                          \
  do {                                                                         \
    const float4 wA = *reinterpret_cast<const float4*>(&wlds[((S)*9+(T))*16 + 0]);  \
    const float4 wB = *reinterpret_cast<const float4*>(&wlds[((S)*9+(T))*16 + 4]);  \
    const float4 wC = *reinterpret_cast<const float4*>(&wlds[((S)*9+(T))*16 + 8]);  \
    const float4 wD = *reinterpret_cast<const float4*>(&wlds[((S)*9+(T))*16 + 12]); \
    y0  = fmaf((XV), wA.x, y0);  y1  = fmaf((XV), wA.y, y1);                   \
    y2  = fmaf((XV), wA.z, y2);  y3  = fmaf((XV), wA.w, y3);                   \
    y4  = fmaf((XV), wB.x, y4);  y5  = fmaf((XV), wB.y, y5);                   \
    y6  = fmaf((XV), wB.z, y6);  y7  = fmaf((XV), wB.w, y7);                   \
    y8  = fmaf((XV), wC.x, y8);  y9  = fmaf((XV), wC.y, y9);                   \
    y10 = fmaf((XV), wC.z, y10); y11 = fmaf((XV), wC.w, y11);                  \
    y12 = fmaf((XV), wD.x, y12); y13 = fmaf((XV), wD.y, y13);                  \
    y14 = fmaf((XV), wD.z, y14); y15 = fmaf((XV), wD.w, y15);                  \
  } while (0)

// One (c,kd) input slice: 9 x-values (3x3 patch), 9 taps * 16 oc FMAs.
#define SLICE(S, P)                                                            \
  do {                                                                         \
    const float xv0 = (P)[0];        const float xv1 = (P)[1];                 \
    const float xv2 = (P)[2];        const float xv3 = (P)[WW];                \
    const float xv4 = (P)[WW + 1];   const float xv5 = (P)[WW + 2];            \
    const float xv6 = (P)[2 * WW];   const float xv7 = (P)[2 * WW + 1];        \
    const float xv8 = (P)[2 * WW + 2];                                         \
    TAP(S, 0, xv0); TAP(S, 1, xv1); TAP(S, 2, xv2);                            \
    TAP(S, 3, xv3); TAP(S, 4, xv4); TAP(S, 5, xv5);                            \
    TAP(S, 6, xv6); TAP(S, 7, xv7); TAP(S, 8, xv8);                            \
  } while (0)

__global__ __launch_bounds__(256, 4) void conv_min_softmax_kernel(
    const float* __restrict__ x, const float* __restrict__ wt,
    float* __restrict__ out) {
  __shared__ __align__(16) float wlds[81 * 16];  // [tap][oc], tap = c*27+kd*9+kh*3+kw... tap-major
  __shared__ float sm[WOUT * 17];                // group-1 partial min, padded stride 17

  const int tid = threadIdx.x;

  // Stage weights transposed: wlds[tap*16 + oc] = wt[oc*81 + tap]
  for (int i = tid; i < 81 * 16; i += 256) {
    const int tap = i >> 4;
    const int oc = i & 15;
    wlds[i] = wt[oc * 81 + tap];
  }
  __syncthreads();

  const int w = tid & 127;
  const int g = tid >> 7;          // dz-group: 0 -> dz 0..10, 1 -> dz 11..21
  const int h = blockIdx.y;
  const int b = blockIdx.z;
  const bool active = (w < WOUT);
  const int wc = active ? w : 0;   // clamp inactive lanes to safe addresses

  // Slice base pointers at dz = g*DZH for each (c, kd): depth index = g*DZH + kd
  const float* xb = x + (((size_t)b * CC * DD) * HH + h) * (size_t)WW + wc;
  const float* p0 = xb + (size_t)(0 * DD + g * DZH + 0) * HW;
  const float* p1 = xb + (size_t)(0 * DD + g * DZH + 1) * HW;
  const float* p2 = xb + (size_t)(0 * DD + g * DZH + 2) * HW;
  const float* p3 = xb + (size_t)(1 * DD + g * DZH + 0) * HW;
  const float* p4 = xb + (size_t)(1 * DD + g * DZH + 1) * HW;
  const float* p5 = xb + (size_t)(1 * DD + g * DZH + 2) * HW;
  const float* p6 = xb + (size_t)(2 * DD + g * DZH + 0) * HW;
  const float* p7 = xb + (size_t)(2 * DD + g * DZH + 1) * HW;
  const float* p8 = xb + (size_t)(2 * DD + g * DZH + 2) * HW;

  float m0 = INFINITY, m1 = INFINITY, m2 = INFINITY, m3 = INFINITY;
  float m4 = INFINITY, m5 = INFINITY, m6 = INFINITY, m7 = INFINITY;
  float m8 = INFINITY, m9 = INFINITY, m10 = INFINITY, m11 = INFINITY;
  float m12 = INFINITY, m13 = INFINITY, m14 = INFINITY, m15 = INFINITY;

  for (int i = 0; i < DZH; ++i) {
    float y0 = 0.f, y1 = 0.f, y2 = 0.f, y3 = 0.f;
    float y4 = 0.f, y5 = 0.f, y6 = 0.f, y7 = 0.f;
    float y8 = 0.f, y9 = 0.f, y10 = 0.f, y11 = 0.f;
    float y12 = 0.f, y13 = 0.f, y14 = 0.f, y15 = 0.f;

    SLICE(0, p0); SLICE(1, p1); SLICE(2, p2);
    SLICE(3, p3); SLICE(4, p4); SLICE(5, p5);
    SLICE(6, p6); SLICE(7, p7); SLICE(8, p8);

    m0 = fminf(m0, y0);   m1 = fminf(m1, y1);
    m2 = fminf(m2, y2);   m3 = fminf(m3, y3);
    m4 = fminf(m4, y4);   m5 = fminf(m5, y5);
    m6 = fminf(m6, y6);   m7 = fminf(m7, y7);
    m8 = fminf(m8, y8);   m9 = fminf(m9, y9);
    m10 = fminf(m10, y10); m11 = fminf(m11, y11);
    m12 = fminf(m12, y12); m13 = fminf(m13, y13);
    m14 = fminf(m14, y14); m15 = fminf(m15, y15);

    p0 += HW; p1 += HW; p2 += HW; p3 += HW; p4 += HW;
    p5 += HW; p6 += HW; p7 += HW; p8 += HW;
  }

  // Group 1 publishes its per-channel mins; group 0 combines + softmax + store.
  if (g == 1 && active) {
    sm[w * 17 + 0] = m0;   sm[w * 17 + 1] = m1;
    sm[w * 17 + 2] = m2;   sm[w * 17 + 3] = m3;
    sm[w * 17 + 4] = m4;   sm[w * 17 + 5] = m5;
    sm[w * 17 + 6] = m6;   sm[w * 17 + 7] = m7;
    sm[w * 17 + 8] = m8;   sm[w * 17 + 9] = m9;
    sm[w * 17 + 10] = m10; sm[w * 17 + 11] = m11;
    sm[w * 17 + 12] = m12; sm[w * 17 + 13] = m13;
    sm[w * 17 + 14] = m14; sm[w * 17 + 15] = m15;
  }
  __syncthreads();

  if (g == 0 && active) {
    m0 = fminf(m0, sm[w * 17 + 0]);   m1 = fminf(m1, sm[w * 17 + 1]);
    m2 = fminf(m2, sm[w * 17 + 2]);   m3 = fminf(m3, sm[w * 17 + 3]);
    m4 = fminf(m4, sm[w * 17 + 4]);   m5 = fminf(m5, sm[w * 17 + 5]);
    m6 = fminf(m6, sm[w * 17 + 6]);   m7 = fminf(m7, sm[w * 17 + 7]);
    m8 = fminf(m8, sm[w * 17 + 8]);   m9 = fminf(m9, sm[w * 17 + 9]);
    m10 = fminf(m10, sm[w * 17 + 10]); m11 = fminf(m11, sm[w * 17 + 11]);
    m12 = fminf(m12, sm[w * 17 + 12]); m13 = fminf(m13, sm[w * 17 + 13]);
    m14 = fminf(m14, sm[w * 17 + 14]); m15 = fminf(m15, sm[w * 17 + 15]);

    float mx = fmaxf(fmaxf(fmaxf(m0, m1), fmaxf(m2, m3)),
                     fmaxf(fmaxf(m4, m5), fmaxf(m6, m7)));
    mx = fmaxf(mx, fmaxf(fmaxf(fmaxf(m8, m9), fmaxf(m10, m11)),
                         fmaxf(fmaxf(m12, m13), fmaxf(m14, m15))));

    const float e0 = __expf(m0 - mx);   const float e1 = __expf(m1 - mx);
    const float e2 = __expf(m2 - mx);   const float e3 = __expf(m3 - mx);
    const float e4 = __expf(m4 - mx);   const float e5 = __expf(m5 - mx);
    const float e6 = __expf(m6 - mx);   const float e7 = __expf(m7 - mx);
    const float e8 = __expf(m8 - mx);   const float e9 = __expf(m9 - mx);
    const float e10 = __expf(m10 - mx); const float e11 = __expf(m11 - mx);
    const float e12 = __expf(m12 - mx); const float e13 = __expf(m13 - mx);
    const float e14 = __expf(m14 - mx); const float e15 = __expf(m15 - mx);

    const float sum = ((e0 + e1) + (e2 + e3)) + ((e4 + e5) + (e6 + e7)) +
                      ((e8 + e9) + (e10 + e11)) + ((e12 + e13) + (e14 + e15));
    const float inv = 1.f / sum;

    float* ob = out + (((size_t)b * OCC) * HOUT + h) * (size_t)WOUT + w;
    const size_t os = (size_t)HOUT * WOUT;
    ob[0 * os] = e0 * inv;   ob[1 * os] = e1 * inv;
    ob[2 * os] = e2 * inv;   ob[3 * os] = e3 * inv;
    ob[4 * os] = e4 * inv;   ob[5 * os] = e5 * inv;
    ob[6 * os] = e6 * inv;   ob[7 * os] = e7 * inv;
    ob[8 * os] = e8 * inv;   ob[9 * os] = e9 * inv;
    ob[10 * os] = e10 * inv; ob[11 * os] = e11 * inv;
    ob[12 * os] = e12 * inv; ob[13 * os] = e13 * inv;
    ob[14 * os] = e14 * inv; ob[15 * os] = e15 * inv;
  }
}

extern "C" void kernel_launch(void* const* d_in, const int* in_sizes, int n_in,
                              void* d_out, int out_size, void* d_ws, size_t ws_size,
                              hipStream_t stream) {
  const float* x = (const float*)d_in[0];
  const float* wt = (const float*)d_in[1];
  float* out = (float*)d_out;

  dim3 grid(1, HOUT, BB);   // 126 * 8 = 1008 blocks
  dim3 block(256, 1, 1);    // 4 waves: 2 dz-groups x 128 lanes (126 active)
  conv_min_softmax_kernel<<<grid, block, 0, stream>>>(x, wt, out);
}